// Round 1
// baseline (129.336 us; speedup 1.0000x reference)
//
#include <hip/hip_runtime.h>
#include <math.h>

#define PI_F 3.14159265358979323846f
#define FLAG_MAGIC 0x9E3779B9u

typedef int v2i __attribute__((ext_vector_type(2)));

__device__ __forceinline__ float rcpf(float x) { return __builtin_amdgcn_rcpf(x); }
__device__ __forceinline__ void fswap(float2& p, float2& q) { float2 t = p; p = q; q = t; }

// ---------------------------------------------------------------------------
// QCNN: one wave per sample, 256-amp state in registers (4 float2/lane).
// qubit0 -> reg bit1, qubit1 -> reg bit0, qubit q in 2..7 -> lane bit (q-2).
// q2,q3: DPP quad_perm; q4,q5,q6: ds_swizzle; q7: v_permlane32_swap (VALU,
// replaces ds_bpermute - removes ~56 ds-pipe ops + lgkm waits per wave).
// ---------------------------------------------------------------------------

template<int Q>
__device__ __forceinline__ float exq(float v) {
    if constexpr (Q == 2)        // lane^1: quad_perm [1,0,3,2]
        return __int_as_float(__builtin_amdgcn_update_dpp(0, __float_as_int(v), 0xB1, 0xF, 0xF, true));
    else if constexpr (Q == 3)   // lane^2: quad_perm [2,3,0,1]
        return __int_as_float(__builtin_amdgcn_update_dpp(0, __float_as_int(v), 0x4E, 0xF, 0xF, true));
    else if constexpr (Q == 4)   // lane^4
        return __int_as_float(__builtin_amdgcn_ds_swizzle(__float_as_int(v), 0x101F));
    else if constexpr (Q == 5)   // lane^8
        return __int_as_float(__builtin_amdgcn_ds_swizzle(__float_as_int(v), 0x201F));
    else if constexpr (Q == 6)   // lane^16
        return __int_as_float(__builtin_amdgcn_ds_swizzle(__float_as_int(v), 0x401F));
    else {                       // lane^32: permlane32_swap, pure VALU
        v2i r = __builtin_amdgcn_permlane32_swap(__float_as_int(v), __float_as_int(v), false, false);
        // r[0] = {v.lo, v.lo}, r[1] = {v.hi, v.hi}
        return __int_as_float((threadIdx.x & 32) ? r[0] : r[1]);
    }
}

// RZ(q,th) = diag(e^{-i th/2}, e^{+i th/2}) - diagonal: no exchange.
template<int Q>
__device__ __forceinline__ void rzg(float2 a[4], float th, int lane) {
    float c = __cosf(0.5f * th), s = __sinf(0.5f * th);
    if constexpr (Q >= 2) {
        float se = ((lane >> (Q - 2)) & 1) ? s : -s;
        #pragma unroll
        for (int r = 0; r < 4; ++r) {
            float nx = c * a[r].x - se * a[r].y;
            float ny = c * a[r].y + se * a[r].x;
            a[r] = make_float2(nx, ny);
        }
    } else {
        #pragma unroll
        for (int r = 0; r < 4; ++r) {
            int bit = (Q == 0) ? (r >> 1) : (r & 1);
            float se = bit ? s : -s;
            float nx = c * a[r].x - se * a[r].y;
            float ny = c * a[r].y + se * a[r].x;
            a[r] = make_float2(nx, ny);
        }
    }
}

// RY(q,th) = [[c,-s],[s,c]]
template<int Q>
__device__ __forceinline__ void ryg(float2 a[4], float th, int lane) {
    float c = __cosf(0.5f * th), s = __sinf(0.5f * th);
    if constexpr (Q >= 2) {
        float se = ((lane >> (Q - 2)) & 1) ? s : -s;
        #pragma unroll
        for (int r = 0; r < 4; ++r) {
            float ox = exq<Q>(a[r].x), oy = exq<Q>(a[r].y);
            a[r] = make_float2(c * a[r].x + se * ox, c * a[r].y + se * oy);
        }
    } else if constexpr (Q == 0) {
        #pragma unroll
        for (int r = 0; r < 2; ++r) {
            float2 lo = a[r], hi = a[r + 2];
            a[r]     = make_float2(c * lo.x - s * hi.x, c * lo.y - s * hi.y);
            a[r + 2] = make_float2(s * lo.x + c * hi.x, s * lo.y + c * hi.y);
        }
    } else {
        #pragma unroll
        for (int r = 0; r < 4; r += 2) {
            float2 lo = a[r], hi = a[r + 1];
            a[r]     = make_float2(c * lo.x - s * hi.x, c * lo.y - s * hi.y);
            a[r + 1] = make_float2(s * lo.x + c * hi.x, s * lo.y + c * hi.y);
        }
    }
}

// CX(C,T): flip T where C==1.
template<int C, int T>
__device__ __forceinline__ void cxg(float2 a[4], int lane) {
    if constexpr (C >= 2) {
        bool cb = (lane >> (C - 2)) & 1;
        #pragma unroll
        for (int r = 0; r < 4; ++r) {
            float ox = exq<T>(a[r].x), oy = exq<T>(a[r].y);
            a[r].x = cb ? ox : a[r].x;
            a[r].y = cb ? oy : a[r].y;
        }
    } else if constexpr (C == 0 && T == 1) {
        fswap(a[2], a[3]);
    } else {
        fswap(a[1], a[3]);
    }
}

// Fused ZFeatureMap gate U = P(2x)*H*P(2x)*H (general 2x2)
template<int Q>
__device__ __forceinline__ void featg(float2 a[4], float xq, int lane) {
    float phi = 2.0f * xq;
    float e1x = __cosf(phi), e1y = __sinf(phi);
    float e2x = e1x * e1x - e1y * e1y;
    float e2y = 2.0f * e1x * e1y;
    float2 u00 = make_float2(0.5f * (1.0f + e1x),  0.5f * e1y);
    float2 u01 = make_float2(0.5f * (1.0f - e1x), -0.5f * e1y);
    float2 u10 = make_float2(0.5f * (e1x - e2x), 0.5f * (e1y - e2y));
    float2 u11 = make_float2(0.5f * (e1x + e2x), 0.5f * (e1y + e2y));
    if constexpr (Q >= 2) {
        bool bset = (lane >> (Q - 2)) & 1;
        float csx = bset ? u11.x : u00.x, csy = bset ? u11.y : u00.y;
        float cox = bset ? u10.x : u01.x, coy = bset ? u10.y : u01.y;
        #pragma unroll
        for (int r = 0; r < 4; ++r) {
            float ox = exq<Q>(a[r].x), oy = exq<Q>(a[r].y);
            float nx = csx * a[r].x - csy * a[r].y + cox * ox - coy * oy;
            float ny = csx * a[r].y + csy * a[r].x + cox * oy + coy * ox;
            a[r] = make_float2(nx, ny);
        }
    } else {
        float2 l, h;
        #define APPL(LO, HI)                                                        \
            l = a[LO]; h = a[HI];                                                   \
            a[LO] = make_float2(u00.x*l.x - u00.y*l.y + u01.x*h.x - u01.y*h.y,      \
                                u00.x*l.y + u00.y*l.x + u01.x*h.y + u01.y*h.x);     \
            a[HI] = make_float2(u10.x*l.x - u10.y*l.y + u11.x*h.x - u11.y*h.y,      \
                                u10.x*l.y + u10.y*l.x + u11.x*h.y + u11.y*h.x);
        if constexpr (Q == 0) { APPL(0, 2) APPL(1, 3) }
        else                  { APPL(0, 1) APPL(2, 3) }
        #undef APPL
    }
}

template<int Q1, int Q2>
__device__ __forceinline__ void convg(float2 a[4], const float* __restrict__ p, int lane) {
    rzg<Q2>(a, -0.5f * PI_F, lane);
    cxg<Q2, Q1>(a, lane);
    rzg<Q1>(a, p[0], lane);
    ryg<Q2>(a, p[1], lane);
    cxg<Q1, Q2>(a, lane);
    ryg<Q2>(a, p[2], lane);
    cxg<Q2, Q1>(a, lane);
    rzg<Q1>(a, 0.5f * PI_F, lane);
}

template<int Q1, int Q2>
__device__ __forceinline__ void poolg(float2 a[4], const float* __restrict__ p, int lane) {
    rzg<Q2>(a, -0.5f * PI_F, lane);
    cxg<Q2, Q1>(a, lane);
    rzg<Q1>(a, p[0], lane);
    ryg<Q2>(a, p[1], lane);
    cxg<Q1, Q2>(a, lane);
    ryg<Q2>(a, p[2], lane);
}

template<int CTRL>
__device__ __forceinline__ float bq(float v) {   // quad_perm broadcast
    return __int_as_float(__builtin_amdgcn_update_dpp(0, __float_as_int(v), CTRL, 0xF, 0xF, true));
}

__device__ __forceinline__ float pick4(bool b0, bool b1, float a0, float a1, float a2, float a3) {
    float t01 = b0 ? a1 : a0;
    float t23 = b0 ? a3 : a2;
    return b1 ? t23 : t01;
}

// ---------------------------------------------------------------------------
// Fused kernel: one dispatch.
//   blocks 0..511 : QCNN producers (4 samples/block, 1 per wave)
//   block 512     : wave 0 = QLSTM consumer; spins on per-sample u64 flags
// Handoff: flg[n] = (float_bits(out_n) << 32) | (MAGIC ^ epoch)   [agent atomics]
// epoch lives at flg+2048, bumped by consumer at end of every launch ->
// keys are never stale across replays; MAGIC != 0 makes any constant ws
// poison pattern P fail the compare (P != MAGIC^P). No memset dispatch needed.
// ---------------------------------------------------------------------------

__global__ __launch_bounds__(256) void fused_kernel(
    const float* __restrict__ x,  const float* __restrict__ w,
    const float* __restrict__ thf, const float* __restrict__ thi,
    const float* __restrict__ thg, const float* __restrict__ tho,
    const float* __restrict__ Wf, const float* __restrict__ bf,
    const float* __restrict__ Wi, const float* __restrict__ bi,
    const float* __restrict__ Wg, const float* __restrict__ bg,
    const float* __restrict__ Wo, const float* __restrict__ bo,
    const float* __restrict__ Wh, const float* __restrict__ bh,
    float* __restrict__ out, unsigned long long* __restrict__ flg) {
    __shared__ __align__(16) float qsh[16 * 132];   // padded rows: conflict-free
    int lane = threadIdx.x & 63;
    int wave = threadIdx.x >> 6;
    unsigned* epoch = (unsigned*)(flg + 2048);

    if (blockIdx.x != 512) {
        // ---------------- QCNN producer ----------------
        unsigned key = FLAG_MAGIC ^ __hip_atomic_load(epoch, __ATOMIC_RELAXED, __HIP_MEMORY_SCOPE_AGENT);
        int n = blockIdx.x * 4 + wave;
        float2 a[4];
        a[0] = make_float2(lane == 0 ? 1.0f : 0.0f, 0.0f);
        a[1] = make_float2(0.0f, 0.0f);
        a[2] = make_float2(0.0f, 0.0f);
        a[3] = make_float2(0.0f, 0.0f);

        const float* xr = x + n * 8;
        featg<0>(a, xr[0], lane);
        featg<1>(a, xr[1], lane);
        featg<2>(a, xr[2], lane);
        featg<3>(a, xr[3], lane);
        featg<4>(a, xr[4], lane);
        featg<5>(a, xr[5], lane);
        featg<6>(a, xr[6], lane);
        featg<7>(a, xr[7], lane);

        convg<0,1>(a, w + 0,  lane);
        convg<2,3>(a, w + 3,  lane);
        convg<4,5>(a, w + 6,  lane);
        convg<6,7>(a, w + 9,  lane);
        poolg<0,1>(a, w + 12, lane);
        poolg<2,3>(a, w + 15, lane);
        poolg<4,5>(a, w + 18, lane);
        poolg<6,7>(a, w + 21, lane);
        convg<0,1>(a, w + 24, lane);
        convg<2,3>(a, w + 27, lane);
        poolg<0,1>(a, w + 30, lane);
        poolg<2,3>(a, w + 33, lane);
        convg<0,1>(a, w + 36, lane);
        poolg<0,1>(a, w + 39, lane);

        // <Z_q7>: q7 = lane bit5
        float ssum = 0.f;
        #pragma unroll
        for (int r = 0; r < 4; ++r)
            ssum += a[r].x * a[r].x + a[r].y * a[r].y;
        ssum = (lane & 32) ? -ssum : ssum;
        // butterfly: DPP for ^1,^2; swizzle for ^4,^8,^16; permlane pair-add for ^32
        ssum += exq<2>(ssum);
        ssum += exq<3>(ssum);
        ssum += exq<4>(ssum);
        ssum += exq<5>(ssum);
        ssum += exq<6>(ssum);
        {
            v2i rr = __builtin_amdgcn_permlane32_swap(__float_as_int(ssum), __float_as_int(ssum), false, false);
            ssum = __int_as_float((threadIdx.x & 32) ? rr[0] : rr[1]) +
                   __int_as_float((threadIdx.x & 32) ? rr[1] : rr[0]);
        }
        if (lane == 0) {
            out[n] = ssum;
            unsigned long long pk = ((unsigned long long)__float_as_uint(ssum) << 32)
                                  | (unsigned long long)key;
            __hip_atomic_store(&flg[n], pk, __ATOMIC_RELAXED, __HIP_MEMORY_SCOPE_AGENT);
        }
        return;
    }

    // ---------------- QLSTM consumer (block 512, wave 0 only) ----------------
    if (wave != 0) return;
    unsigned key = FLAG_MAGIC ^ __hip_atomic_load(epoch, __ATOMIC_RELAXED, __HIP_MEMORY_SCOPE_AGENT);

    // spin on per-sample flags; payload rides inside the atomic (no data fence)
    for (int j = 0; j < 32; ++j) {
        int idx = j * 64 + lane;
        unsigned long long v;
        do {
            v = __hip_atomic_load(&flg[idx], __ATOMIC_RELAXED, __HIP_MEMORY_SCOPE_AGENT);
        } while ((unsigned)v != key);
        qsh[(idx >> 7) * 132 + (idx & 127)] = __uint_as_float((unsigned)(v >> 32));
    }
    __builtin_amdgcn_wave_barrier();     // single wave: LDS ops program-ordered

    int b = lane >> 2, q = lane & 3;
    bool qb0 = q & 1, qb1 = q & 2;
    const float* Wp = (q == 0) ? Wf : (q == 1) ? Wi : (q == 2) ? Wg : Wo;
    const float* bp = (q == 0) ? bf : (q == 1) ? bi : (q == 2) ? bg : bo;
    const float* tp = (q == 0) ? thf : (q == 1) ? thi : (q == 2) ? thg : tho;

    float W[20], av[4];
    #pragma unroll
    for (int k = 0; k < 20; ++k) W[k] = Wp[k];
    #pragma unroll
    for (int r = 0; r < 4; ++r) av[r] = bp[r] + tp[r];

    // gate-q nonlinearity constants (tanh for q==2, sigmoid otherwise)
    float nA = (q == 2) ? 1.0f : 0.0f;
    float nB = (q == 2) ? -2.0f : 1.0f;
    float nK = (q == 2) ? 2.0f : -1.0f;

    float c = 0.f;                       // state row q only
    float h0 = 0.f, h1 = 0.f, h2 = 0.f, h3 = 0.f;   // broadcast h (all rows)
    const float* qrow = &qsh[b * 132];
    float xv = qrow[0];

    for (int t = 0; t < 128; ++t) {
        float xn = qrow[t + 1];          // prefetch (t=127 reads row padding, unused)
        float vA = av[0] + W[0]*xv  + W[1]*h0  + W[2]*h1  + W[3]*h2  + W[4]*h3;
        float vB = av[1] + W[5]*xv  + W[6]*h0  + W[7]*h1  + W[8]*h2  + W[9]*h3;
        float vC = av[2] + W[10]*xv + W[11]*h0 + W[12]*h1 + W[13]*h2 + W[14]*h3;
        float vD = av[3] + W[15]*xv + W[16]*h0 + W[17]*h1 + W[18]*h2 + W[19]*h3;
        float cA = __cosf(vA), cB = __cosf(vB), cC = __cosf(vC), cD = __cosf(vD);
        float r1 = cA * cB, r2 = r1 * cC, r3 = r2 * cD, r0 = cB * (cC * cD);
        // unified nonlinearity for this lane's gate
        float E0 = __expf(nK * r0), E1 = __expf(nK * r1);
        float E2 = __expf(nK * r2), E3 = __expf(nK * r3);
        float n0 = nA + nB * rcpf(E0 + 1.0f);
        float n1 = nA + nB * rcpf(E1 + 1.0f);
        float n2 = nA + nB * rcpf(E2 + 1.0f);
        float n3 = nA + nB * rcpf(E3 + 1.0f);
        // broadcast all 16 gate x row values across the quad
        float F0 = bq<0x00>(n0), F1 = bq<0x00>(n1), F2 = bq<0x00>(n2), F3 = bq<0x00>(n3);
        float I0 = bq<0x55>(n0), I1 = bq<0x55>(n1), I2 = bq<0x55>(n2), I3 = bq<0x55>(n3);
        float G0 = bq<0xAA>(n0), G1 = bq<0xAA>(n1), G2 = bq<0xAA>(n2), G3 = bq<0xAA>(n3);
        float O0 = bq<0xFF>(n0), O1 = bq<0xFF>(n1), O2 = bq<0xFF>(n2), O3 = bq<0xFF>(n3);
        // pick own row q
        float F = pick4(qb0, qb1, F0, F1, F2, F3);
        float I = pick4(qb0, qb1, I0, I1, I2, I3);
        float G = pick4(qb0, qb1, G0, G1, G2, G3);
        float O = pick4(qb0, qb1, O0, O1, O2, O3);
        c = F * c + I * G;
        float Ec = __expf(2.0f * c);
        float tau = 1.0f - 2.0f * rcpf(Ec + 1.0f);
        float hq = O * tau;
        h0 = bq<0x00>(hq);
        h1 = bq<0x55>(hq);
        h2 = bq<0xAA>(hq);
        h3 = bq<0xFF>(hq);
        xv = xn;
    }

    if (q == 0)
        out[2048 + b] = bh[0] + Wh[0]*h0 + Wh[1]*h1 + Wh[2]*h2 + Wh[3]*h3;

    // bump epoch so next replay's key differs from this run's flags
    if (lane == 0)
        __hip_atomic_fetch_add(epoch, 1u, __ATOMIC_RELAXED, __HIP_MEMORY_SCOPE_AGENT);
}

extern "C" void kernel_launch(void* const* d_in, const int* in_sizes, int n_in,
                              void* d_out, int out_size, void* d_ws, size_t ws_size,
                              hipStream_t stream) {
    fused_kernel<<<513, 256, 0, stream>>>(
        (const float*)d_in[0],  (const float*)d_in[1],
        (const float*)d_in[2],  (const float*)d_in[3],
        (const float*)d_in[4],  (const float*)d_in[5],
        (const float*)d_in[6],  (const float*)d_in[7],
        (const float*)d_in[8],  (const float*)d_in[9],
        (const float*)d_in[10], (const float*)d_in[11],
        (const float*)d_in[12], (const float*)d_in[13],
        (const float*)d_in[14], (const float*)d_in[15],
        (float*)d_out, (unsigned long long*)d_ws);
}

// Round 4
// 122.620 us; speedup vs baseline: 1.0548x; 1.0548x over previous
//
#include <hip/hip_runtime.h>
#include <math.h>

#define PI_F 3.14159265358979323846f
#define FLAG_MAGIC 0x9E3779B9u

typedef int v2i __attribute__((ext_vector_type(2)));

__device__ __forceinline__ float rcpf(float x) { return __builtin_amdgcn_rcpf(x); }
__device__ __forceinline__ void fswap(float2& p, float2& q) { float2 t = p; p = q; q = t; }

// ---------------------------------------------------------------------------
// QCNN: one wave per sample, 256-amp state in registers (4 float2/lane).
// qubit0 -> reg bit1, qubit1 -> reg bit0, qubit q in 2..7 -> lane bit (q-2).
// ---------------------------------------------------------------------------

template<int Q>
__device__ __forceinline__ float exq(float v) {
    if constexpr (Q == 2)        // lane^1: quad_perm [1,0,3,2]
        return __int_as_float(__builtin_amdgcn_update_dpp(0, __float_as_int(v), 0xB1, 0xF, 0xF, true));
    else if constexpr (Q == 3)   // lane^2: quad_perm [2,3,0,1]
        return __int_as_float(__builtin_amdgcn_update_dpp(0, __float_as_int(v), 0x4E, 0xF, 0xF, true));
    else if constexpr (Q == 4)   // lane^4
        return __int_as_float(__builtin_amdgcn_ds_swizzle(__float_as_int(v), 0x101F));
    else if constexpr (Q == 5)   // lane^8
        return __int_as_float(__builtin_amdgcn_ds_swizzle(__float_as_int(v), 0x201F));
    else if constexpr (Q == 6)   // lane^16
        return __int_as_float(__builtin_amdgcn_ds_swizzle(__float_as_int(v), 0x401F));
    else {                       // lane^32: permlane32_swap, pure VALU
        v2i r = __builtin_amdgcn_permlane32_swap(__float_as_int(v), __float_as_int(v), false, false);
        return __int_as_float((threadIdx.x & 32) ? r[0] : r[1]);
    }
}

template<int Q>
__device__ __forceinline__ void rzg(float2 a[4], float th, int lane) {
    float c = __cosf(0.5f * th), s = __sinf(0.5f * th);
    if constexpr (Q >= 2) {
        float se = ((lane >> (Q - 2)) & 1) ? s : -s;
        #pragma unroll
        for (int r = 0; r < 4; ++r) {
            float nx = c * a[r].x - se * a[r].y;
            float ny = c * a[r].y + se * a[r].x;
            a[r] = make_float2(nx, ny);
        }
    } else {
        #pragma unroll
        for (int r = 0; r < 4; ++r) {
            int bit = (Q == 0) ? (r >> 1) : (r & 1);
            float se = bit ? s : -s;
            float nx = c * a[r].x - se * a[r].y;
            float ny = c * a[r].y + se * a[r].x;
            a[r] = make_float2(nx, ny);
        }
    }
}

template<int Q>
__device__ __forceinline__ void ryg(float2 a[4], float th, int lane) {
    float c = __cosf(0.5f * th), s = __sinf(0.5f * th);
    if constexpr (Q >= 2) {
        float se = ((lane >> (Q - 2)) & 1) ? s : -s;
        #pragma unroll
        for (int r = 0; r < 4; ++r) {
            float ox = exq<Q>(a[r].x), oy = exq<Q>(a[r].y);
            a[r] = make_float2(c * a[r].x + se * ox, c * a[r].y + se * oy);
        }
    } else if constexpr (Q == 0) {
        #pragma unroll
        for (int r = 0; r < 2; ++r) {
            float2 lo = a[r], hi = a[r + 2];
            a[r]     = make_float2(c * lo.x - s * hi.x, c * lo.y - s * hi.y);
            a[r + 2] = make_float2(s * lo.x + c * hi.x, s * lo.y + c * hi.y);
        }
    } else {
        #pragma unroll
        for (int r = 0; r < 4; r += 2) {
            float2 lo = a[r], hi = a[r + 1];
            a[r]     = make_float2(c * lo.x - s * hi.x, c * lo.y - s * hi.y);
            a[r + 1] = make_float2(s * lo.x + c * hi.x, s * lo.y + c * hi.y);
        }
    }
}

template<int C, int T>
__device__ __forceinline__ void cxg(float2 a[4], int lane) {
    if constexpr (C >= 2) {
        bool cb = (lane >> (C - 2)) & 1;
        #pragma unroll
        for (int r = 0; r < 4; ++r) {
            float ox = exq<T>(a[r].x), oy = exq<T>(a[r].y);
            a[r].x = cb ? ox : a[r].x;
            a[r].y = cb ? oy : a[r].y;
        }
    } else if constexpr (C == 0 && T == 1) {
        fswap(a[2], a[3]);
    } else {
        fswap(a[1], a[3]);
    }
}

template<int Q>
__device__ __forceinline__ void featg(float2 a[4], float xq, int lane) {
    float phi = 2.0f * xq;
    float e1x = __cosf(phi), e1y = __sinf(phi);
    float e2x = e1x * e1x - e1y * e1y;
    float e2y = 2.0f * e1x * e1y;
    float2 u00 = make_float2(0.5f * (1.0f + e1x),  0.5f * e1y);
    float2 u01 = make_float2(0.5f * (1.0f - e1x), -0.5f * e1y);
    float2 u10 = make_float2(0.5f * (e1x - e2x), 0.5f * (e1y - e2y));
    float2 u11 = make_float2(0.5f * (e1x + e2x), 0.5f * (e1y + e2y));
    if constexpr (Q >= 2) {
        bool bset = (lane >> (Q - 2)) & 1;
        float csx = bset ? u11.x : u00.x, csy = bset ? u11.y : u00.y;
        float cox = bset ? u10.x : u01.x, coy = bset ? u10.y : u01.y;
        #pragma unroll
        for (int r = 0; r < 4; ++r) {
            float ox = exq<Q>(a[r].x), oy = exq<Q>(a[r].y);
            float nx = csx * a[r].x - csy * a[r].y + cox * ox - coy * oy;
            float ny = csx * a[r].y + csy * a[r].x + cox * oy + coy * ox;
            a[r] = make_float2(nx, ny);
        }
    } else {
        float2 l, h;
        #define APPL(LO, HI)                                                        \
            l = a[LO]; h = a[HI];                                                   \
            a[LO] = make_float2(u00.x*l.x - u00.y*l.y + u01.x*h.x - u01.y*h.y,      \
                                u00.x*l.y + u00.y*l.x + u01.x*h.y + u01.y*h.x);     \
            a[HI] = make_float2(u10.x*l.x - u10.y*l.y + u11.x*h.x - u11.y*h.y,      \
                                u10.x*l.y + u10.y*l.x + u11.x*h.y + u11.y*h.x);
        if constexpr (Q == 0) { APPL(0, 2) APPL(1, 3) }
        else                  { APPL(0, 1) APPL(2, 3) }
        #undef APPL
    }
}

template<int Q1, int Q2>
__device__ __forceinline__ void convg(float2 a[4], const float* __restrict__ p, int lane) {
    rzg<Q2>(a, -0.5f * PI_F, lane);
    cxg<Q2, Q1>(a, lane);
    rzg<Q1>(a, p[0], lane);
    ryg<Q2>(a, p[1], lane);
    cxg<Q1, Q2>(a, lane);
    ryg<Q2>(a, p[2], lane);
    cxg<Q2, Q1>(a, lane);
    rzg<Q1>(a, 0.5f * PI_F, lane);
}

template<int Q1, int Q2>
__device__ __forceinline__ void poolg(float2 a[4], const float* __restrict__ p, int lane) {
    rzg<Q2>(a, -0.5f * PI_F, lane);
    cxg<Q2, Q1>(a, lane);
    rzg<Q1>(a, p[0], lane);
    ryg<Q2>(a, p[1], lane);
    cxg<Q1, Q2>(a, lane);
    ryg<Q2>(a, p[2], lane);
}

template<int CTRL>
__device__ __forceinline__ float bq(float v) {   // quad_perm broadcast
    return __int_as_float(__builtin_amdgcn_update_dpp(0, __float_as_int(v), CTRL, 0xF, 0xF, true));
}

__device__ __forceinline__ float pick4(bool b0, bool b1, float a0, float a1, float a2, float a3) {
    float t01 = b0 ? a1 : a0;
    float t23 = b0 ? a3 : a2;
    return b1 ? t23 : t01;
}

// ---------------------------------------------------------------------------
// Fused kernel, PIPELINED handoff. One dispatch.
//   blocks 0..511 : QCNN producers. Flag index n = blockIdx*4 + wave is
//                   TIMESTEP-MAJOR: n = t*16 + b  (t = n>>4, b = n&15), so
//                   early blocks produce early timesteps.
//   block 512     : wave 0 = QLSTM consumer. Stages 64-flag chunks
//                   (4 timesteps x 16 batches) with 1-chunk lookahead and
//                   processes LSTM steps as chunks arrive -> LSTM streams
//                   behind the producer wavefront instead of waiting ~13us.
// Handoff: flg[n] = (float_bits(qcnn_n) << 32) | (MAGIC ^ epoch); epoch at
// flg+2048, bumped by consumer each launch (replay/poison-safe; v1-proven).
//
// FORENSIC NOTE (rounds 2/3): both failed with identical absmax 2.634888e-1
// = max|ref logits| with actual logits == 0 => consumer output never stored.
// Suspect set quarantined from this version: 8-DPP quad transpose,
// s_setprio, asm-operand W pin. LSTM per-step arithmetic below is VERBATIM
// the passing v1 code (exp-based; ~1e-7/step error budget, amplified ~4e4x
// by the recurrence). W-residency is addressed declaratively via
// __launch_bounds__(256,1) instead of the asm pin.
// ---------------------------------------------------------------------------

__device__ __forceinline__ void stage_chunk(int m, int lane, unsigned key,
                                            unsigned long long* __restrict__ flg,
                                            float* qsh) {
    int idx = m * 64 + lane;             // idx = t*16 + b
    unsigned long long v = __hip_atomic_load(&flg[idx], __ATOMIC_RELAXED, __HIP_MEMORY_SCOPE_AGENT);
    while ((unsigned)v != key) {
        __builtin_amdgcn_s_sleep(1);     // gentle spin: producers share the CU
        v = __hip_atomic_load(&flg[idx], __ATOMIC_RELAXED, __HIP_MEMORY_SCOPE_AGENT);
    }
    qsh[(idx & 15) * 132 + (idx >> 4)] = __uint_as_float((unsigned)(v >> 32));
}

__global__ __launch_bounds__(256, 1) void fused_kernel(
    const float* __restrict__ x,  const float* __restrict__ w,
    const float* __restrict__ thf, const float* __restrict__ thi,
    const float* __restrict__ thg, const float* __restrict__ tho,
    const float* __restrict__ Wf, const float* __restrict__ bf,
    const float* __restrict__ Wi, const float* __restrict__ bi,
    const float* __restrict__ Wg, const float* __restrict__ bg,
    const float* __restrict__ Wo, const float* __restrict__ bo,
    const float* __restrict__ Wh, const float* __restrict__ bh,
    float* __restrict__ out, unsigned long long* __restrict__ flg) {
    __shared__ __align__(16) float qsh[16 * 132];   // padded rows: conflict-free
    int lane = threadIdx.x & 63;
    int wave = threadIdx.x >> 6;
    unsigned* epoch = (unsigned*)(flg + 2048);

    if (blockIdx.x != 512) {
        // ---------------- QCNN producer ----------------
        unsigned key = FLAG_MAGIC ^ __hip_atomic_load(epoch, __ATOMIC_RELAXED, __HIP_MEMORY_SCOPE_AGENT);
        int n = blockIdx.x * 4 + wave;   // flag index, timestep-major
        int bb = n & 15, tt = n >> 4;    // batch, timestep
        int sidx = bb * 128 + tt;        // x/out layout index (batch-major)
        float2 a[4];
        a[0] = make_float2(lane == 0 ? 1.0f : 0.0f, 0.0f);
        a[1] = make_float2(0.0f, 0.0f);
        a[2] = make_float2(0.0f, 0.0f);
        a[3] = make_float2(0.0f, 0.0f);

        const float* xr = x + sidx * 8;
        featg<0>(a, xr[0], lane);
        featg<1>(a, xr[1], lane);
        featg<2>(a, xr[2], lane);
        featg<3>(a, xr[3], lane);
        featg<4>(a, xr[4], lane);
        featg<5>(a, xr[5], lane);
        featg<6>(a, xr[6], lane);
        featg<7>(a, xr[7], lane);

        convg<0,1>(a, w + 0,  lane);
        convg<2,3>(a, w + 3,  lane);
        convg<4,5>(a, w + 6,  lane);
        convg<6,7>(a, w + 9,  lane);
        poolg<0,1>(a, w + 12, lane);
        poolg<2,3>(a, w + 15, lane);
        poolg<4,5>(a, w + 18, lane);
        poolg<6,7>(a, w + 21, lane);
        convg<0,1>(a, w + 24, lane);
        convg<2,3>(a, w + 27, lane);
        poolg<0,1>(a, w + 30, lane);
        poolg<2,3>(a, w + 33, lane);
        convg<0,1>(a, w + 36, lane);
        poolg<0,1>(a, w + 39, lane);

        // <Z_q7>: q7 = lane bit5
        float ssum = 0.f;
        #pragma unroll
        for (int r = 0; r < 4; ++r)
            ssum += a[r].x * a[r].x + a[r].y * a[r].y;
        ssum = (lane & 32) ? -ssum : ssum;
        ssum += exq<2>(ssum);
        ssum += exq<3>(ssum);
        ssum += exq<4>(ssum);
        ssum += exq<5>(ssum);
        ssum += exq<6>(ssum);
        {
            v2i rr = __builtin_amdgcn_permlane32_swap(__float_as_int(ssum), __float_as_int(ssum), false, false);
            ssum = __int_as_float((threadIdx.x & 32) ? rr[0] : rr[1]) +
                   __int_as_float((threadIdx.x & 32) ? rr[1] : rr[0]);
        }
        if (lane == 0) {
            out[sidx] = ssum;
            unsigned long long pk = ((unsigned long long)__float_as_uint(ssum) << 32)
                                  | (unsigned long long)key;
            __hip_atomic_store(&flg[n], pk, __ATOMIC_RELAXED, __HIP_MEMORY_SCOPE_AGENT);
        }
        return;
    }

    // ---------------- QLSTM consumer (block 512, wave 0 only) ----------------
    if (wave != 0) return;
    unsigned key = FLAG_MAGIC ^ __hip_atomic_load(epoch, __ATOMIC_RELAXED, __HIP_MEMORY_SCOPE_AGENT);

    stage_chunk(0, lane, key, flg, qsh);      // timesteps 0..3
    __builtin_amdgcn_wave_barrier();

    int b = lane >> 2, q = lane & 3;
    bool qb0 = q & 1, qb1 = q & 2;
    const float* Wp = (q == 0) ? Wf : (q == 1) ? Wi : (q == 2) ? Wg : Wo;
    const float* bp = (q == 0) ? bf : (q == 1) ? bi : (q == 2) ? bg : bo;
    const float* tp = (q == 0) ? thf : (q == 1) ? thi : (q == 2) ? thg : tho;

    float W[20], av[4];
    #pragma unroll
    for (int k = 0; k < 20; ++k) W[k] = Wp[k];
    #pragma unroll
    for (int r = 0; r < 4; ++r) av[r] = bp[r] + tp[r];

    // gate-q nonlinearity constants (tanh for q==2, sigmoid otherwise)
    float nA = (q == 2) ? 1.0f : 0.0f;
    float nB = (q == 2) ? -2.0f : 1.0f;
    float nK = (q == 2) ? 2.0f : -1.0f;

    float c = 0.f;
    float h0 = 0.f, h1 = 0.f, h2 = 0.f, h3 = 0.f;
    const float* qrow = &qsh[b * 132];

    for (int j = 0; j < 32; ++j) {
        if (j < 31) stage_chunk(j + 1, lane, key, flg, qsh);  // lookahead
        __builtin_amdgcn_wave_barrier();
        #pragma unroll
        for (int k = 0; k < 4; ++k) {
            int t = 4 * j + k;
            float xv = qrow[t];
            float vA = av[0] + W[0]*xv  + W[1]*h0  + W[2]*h1  + W[3]*h2  + W[4]*h3;
            float vB = av[1] + W[5]*xv  + W[6]*h0  + W[7]*h1  + W[8]*h2  + W[9]*h3;
            float vC = av[2] + W[10]*xv + W[11]*h0 + W[12]*h1 + W[13]*h2 + W[14]*h3;
            float vD = av[3] + W[15]*xv + W[16]*h0 + W[17]*h1 + W[18]*h2 + W[19]*h3;
            float cA = __cosf(vA), cB = __cosf(vB), cC = __cosf(vC), cD = __cosf(vD);
            float r1 = cA * cB, r2 = r1 * cC, r3 = r2 * cD, r0 = cB * (cC * cD);
            // unified nonlinearity (verbatim passing-v1: exp-based)
            float E0 = __expf(nK * r0), E1 = __expf(nK * r1);
            float E2 = __expf(nK * r2), E3 = __expf(nK * r3);
            float n0 = nA + nB * rcpf(E0 + 1.0f);
            float n1 = nA + nB * rcpf(E1 + 1.0f);
            float n2 = nA + nB * rcpf(E2 + 1.0f);
            float n3 = nA + nB * rcpf(E3 + 1.0f);
            // broadcast all 16 gate x row values across the quad (v1-verbatim)
            float F0 = bq<0x00>(n0), F1 = bq<0x00>(n1), F2 = bq<0x00>(n2), F3 = bq<0x00>(n3);
            float I0 = bq<0x55>(n0), I1 = bq<0x55>(n1), I2 = bq<0x55>(n2), I3 = bq<0x55>(n3);
            float G0 = bq<0xAA>(n0), G1 = bq<0xAA>(n1), G2 = bq<0xAA>(n2), G3 = bq<0xAA>(n3);
            float O0 = bq<0xFF>(n0), O1 = bq<0xFF>(n1), O2 = bq<0xFF>(n2), O3 = bq<0xFF>(n3);
            float F = pick4(qb0, qb1, F0, F1, F2, F3);
            float I = pick4(qb0, qb1, I0, I1, I2, I3);
            float G = pick4(qb0, qb1, G0, G1, G2, G3);
            float O = pick4(qb0, qb1, O0, O1, O2, O3);
            c = F * c + I * G;
            float Ec = __expf(2.0f * c);
            float tau = 1.0f - 2.0f * rcpf(Ec + 1.0f);
            float hq = O * tau;
            h0 = bq<0x00>(hq);
            h1 = bq<0x55>(hq);
            h2 = bq<0xAA>(hq);
            h3 = bq<0xFF>(hq);
        }
    }

    if (q == 0)
        out[2048 + b] = bh[0] + Wh[0]*h0 + Wh[1]*h1 + Wh[2]*h2 + Wh[3]*h3;

    if (lane == 0)
        __hip_atomic_fetch_add(epoch, 1u, __ATOMIC_RELAXED, __HIP_MEMORY_SCOPE_AGENT);
}

extern "C" void kernel_launch(void* const* d_in, const int* in_sizes, int n_in,
                              void* d_out, int out_size, void* d_ws, size_t ws_size,
                              hipStream_t stream) {
    fused_kernel<<<513, 256, 0, stream>>>(
        (const float*)d_in[0],  (const float*)d_in[1],
        (const float*)d_in[2],  (const float*)d_in[3],
        (const float*)d_in[4],  (const float*)d_in[5],
        (const float*)d_in[6],  (const float*)d_in[7],
        (const float*)d_in[8],  (const float*)d_in[9],
        (const float*)d_in[10], (const float*)d_in[11],
        (const float*)d_in[12], (const float*)d_in[13],
        (const float*)d_in[14], (const float*)d_in[15],
        (float*)d_out, (unsigned long long*)d_ws);
}